// Round 4
// baseline (145.381 us; speedup 1.0000x reference)
//
#include <hip/hip_runtime.h>
#include <hip/hip_cooperative_groups.h>

namespace cg = cooperative_groups;

#define SEQ  200
#define DIM  512
#define NBLK 512   // each block handles rows b and b+NBLK

// ---------------- Fused cooperative kernel ----------------------------------
// Phase 1: stage indices+freqs for this block's 2 rows, accumulate local sum
//          of f^2 (grid collectively covers all of xs exactly once) ->
//          atomicAdd(double) into ws.
// Phase 2: UNNORMALIZED pool into registers (inv_norm is a global scalar, so
//          it commutes out of the sum).
// Phase 3: grid.sync(); read total ssq; scale + write final out.
__global__ __launch_bounds__(512) void fused_kernel(const int* __restrict__ xs,
                                                    const float* __restrict__ W,
                                                    const float* __restrict__ freqs,
                                                    double* __restrict__ ssq,
                                                    float* __restrict__ out,
                                                    int bsz) {
    __shared__ int    s_idx[2][SEQ];
    __shared__ float  s_f[2][SEQ];
    __shared__ float  s_part[2][3][DIM];
    __shared__ double s_w[8];
    __shared__ float  s_inv;

    const int tid     = threadIdx.x;
    const int group   = tid >> 7;     // 0..3
    const int lane128 = tid & 127;
    const int col4    = lane128 * 4;

    // ---- Phase 1: stage + local ssq partial ----
    float ssl = 0.f;
    for (int r = 0; r < 2; ++r) {
        const int b = blockIdx.x + r * NBLK;
        if (b < bsz) {
            for (int l = tid; l < SEQ; l += 512) {
                int   idx = xs[(size_t)b * SEQ + l];
                float f   = freqs[idx];
                s_idx[r][l] = idx;
                s_f[r][l]   = f;
                ssl += f * f;
            }
        }
    }
    // block-reduce ssl -> one double atomicAdd
    double accd = (double)ssl;
    for (int off = 32; off > 0; off >>= 1)
        accd += __shfl_down(accd, off, 64);
    const int lane = tid & 63, wave = tid >> 6;
    if (lane == 0) s_w[wave] = accd;
    __syncthreads();
    if (tid == 0) {
        double t = 0.0;
        for (int w = 0; w < 8; ++w) t += s_w[w];
        atomicAdd(ssq, t);
    }

    // ---- Phase 2: unnormalized pool ----
    float4 acc[2];
    for (int r = 0; r < 2; ++r) {
        float4 a = make_float4(0.f, 0.f, 0.f, 0.f);
        const int b = blockIdx.x + r * NBLK;
        if (b < bsz) {
            #pragma unroll 4
            for (int l = group; l < SEQ; l += 4) {
                const int   idx = s_idx[r][l];
                const float s   = s_f[r][l];
                const float4 w  = *reinterpret_cast<const float4*>(
                    W + (size_t)idx * DIM + col4);
                a.x += s * w.x;
                a.y += s * w.y;
                a.z += s * w.z;
                a.w += s * w.w;
            }
        }
        acc[r] = a;
    }
    // combine the 4 groups' partials via LDS
    if (group > 0) {
        *reinterpret_cast<float4*>(&s_part[0][group - 1][col4]) = acc[0];
        *reinterpret_cast<float4*>(&s_part[1][group - 1][col4]) = acc[1];
    }
    __syncthreads();
    if (group == 0) {
        for (int g = 0; g < 3; ++g) {
            const float4 p0 = *reinterpret_cast<const float4*>(&s_part[0][g][col4]);
            const float4 p1 = *reinterpret_cast<const float4*>(&s_part[1][g][col4]);
            acc[0].x += p0.x; acc[0].y += p0.y; acc[0].z += p0.z; acc[0].w += p0.w;
            acc[1].x += p1.x; acc[1].y += p1.y; acc[1].z += p1.z; acc[1].w += p1.w;
        }
    }

    // ---- Phase 3: global norm, scale, write ----
    cg::this_grid().sync();
    if (tid == 0) {
        double v = __hip_atomic_load(ssq, __ATOMIC_ACQUIRE, __HIP_MEMORY_SCOPE_AGENT);
        s_inv = (float)(1.0 / sqrt(v));
    }
    __syncthreads();
    const float inv = s_inv;
    if (group == 0) {
        for (int r = 0; r < 2; ++r) {
            const int b = blockIdx.x + r * NBLK;
            if (b < bsz) {
                float4 o = acc[r];
                o.x *= inv; o.y *= inv; o.z *= inv; o.w *= inv;
                *reinterpret_cast<float4*>(out + (size_t)b * DIM + col4) = o;
            }
        }
    }
}

// ---------------- Fallback (non-cooperative) path ----------------------------
__global__ __launch_bounds__(256) void ssq_kernel(const int* __restrict__ xs,
                                                  const float* __restrict__ freqs,
                                                  double* __restrict__ ssq,
                                                  int n) {
    double acc = 0.0;
    for (int i = blockIdx.x * blockDim.x + threadIdx.x; i < n;
         i += gridDim.x * blockDim.x) {
        float f = freqs[xs[i]];
        acc += (double)f * (double)f;
    }
    for (int off = 32; off > 0; off >>= 1)
        acc += __shfl_down(acc, off, 64);
    __shared__ double s_w[4];
    if ((threadIdx.x & 63) == 0) s_w[threadIdx.x >> 6] = acc;
    __syncthreads();
    if (threadIdx.x == 0)
        atomicAdd(ssq, s_w[0] + s_w[1] + s_w[2] + s_w[3]);
}

__global__ __launch_bounds__(512) void pool_kernel(const int* __restrict__ xs,
                                                   const float* __restrict__ W,
                                                   const float* __restrict__ freqs,
                                                   const double* __restrict__ ssq,
                                                   float* __restrict__ out) {
    __shared__ int   s_idx[SEQ];
    __shared__ float s_scl[SEQ];
    __shared__ float s_part[3][DIM];
    const int b   = blockIdx.x;
    const int tid = threadIdx.x;
    const float inv_norm = (float)(1.0 / sqrt(ssq[0]));
    for (int l = tid; l < SEQ; l += 512) {
        int idx  = xs[(size_t)b * SEQ + l];
        s_idx[l] = idx;
        s_scl[l] = freqs[idx] * inv_norm;
    }
    __syncthreads();
    const int group = tid >> 7, lane128 = tid & 127, col4 = lane128 * 4;
    float4 acc = make_float4(0.f, 0.f, 0.f, 0.f);
    #pragma unroll 4
    for (int l = group; l < SEQ; l += 4) {
        const int   idx = s_idx[l];
        const float s   = s_scl[l];
        const float4 w  = *reinterpret_cast<const float4*>(
            W + (size_t)idx * DIM + col4);
        acc.x += s * w.x; acc.y += s * w.y; acc.z += s * w.z; acc.w += s * w.w;
    }
    if (group > 0)
        *reinterpret_cast<float4*>(&s_part[group - 1][col4]) = acc;
    __syncthreads();
    if (group == 0) {
        for (int g = 0; g < 3; ++g) {
            const float4 p = *reinterpret_cast<const float4*>(&s_part[g][col4]);
            acc.x += p.x; acc.y += p.y; acc.z += p.z; acc.w += p.w;
        }
        *reinterpret_cast<float4*>(out + (size_t)b * DIM + col4) = acc;
    }
}

extern "C" void kernel_launch(void* const* d_in, const int* in_sizes, int n_in,
                              void* d_out, int out_size, void* d_ws, size_t ws_size,
                              hipStream_t stream) {
    const int*   xs    = (const int*)d_in[0];    // [1024, 200] int32
    const float* W     = (const float*)d_in[1];  // [100000, 512] f32
    const float* freqs = (const float*)d_in[2];  // [100000] f32
    float*  out = (float*)d_out;                 // [1024, 512] f32
    double* ssq = (double*)d_ws;

    const int n   = in_sizes[0];   // 204800
    int bsz = n / SEQ;             // 1024

    hipMemsetAsync(d_ws, 0, sizeof(double), stream);

    void* args[] = {(void*)&xs, (void*)&W, (void*)&freqs,
                    (void*)&ssq, (void*)&out, (void*)&bsz};
    hipError_t e = hipLaunchCooperativeKernel((const void*)fused_kernel,
                                              dim3(NBLK), dim3(512),
                                              args, 0, stream);
    if (e != hipSuccess) {
        (void)hipGetLastError();  // clear, take the 2-kernel path
        ssq_kernel<<<400, 256, 0, stream>>>(xs, freqs, ssq, n);
        pool_kernel<<<bsz, 512, 0, stream>>>(xs, W, freqs, ssq, out);
    }
}